// Round 1
// baseline (5668.661 us; speedup 1.0000x reference)
//
#include <hip/hip_runtime.h>

// ResidualQuantizer: 3-level RVQ, levels 0/1 argmin, level 2 = 50-iter log-domain
// Sinkhorn reduced to potential form (see header comment math):
//   M_ij = 2t*cross(r_i, c_j),  t = 1/(amp*eps)
//   row:  rowLSE_i = LSE_j(M_ij + w_j)
//   col:  sigma_j  = sum_i exp(M_ij + w_j - rowLSE_i)   (terms <= 1, no max needed)
//         w_j     += log(B/K) - log(sigma_j)
//   codes2_i = argmax_j(M_ij + w_j)
// All outputs written as float32 into the single flat d_out buffer
// (codes encoded as exact float integers).

#define BSZ   262144
#define DIM   32
#define KK    256
#define CHUNK 128
#define NBLK  (BSZ / CHUNK)   // 2048
#define LROW  36              // padded LDS row stride (16B aligned, bank-spread)
#define SKEPS 0.003f
#define NIT   50

// workspace float/uint offsets
#define WS_SSQ  0
#define WS_MINK 1
#define WS_MAXK 2
#define WS_TWOT 3
#define WS_W    8      // 256 floats
#define WS_PART 512    // NBLK*256 floats  (~2.0 MB)

// d_out float offsets (return order: codes0, codes1, codes2, quantized, loss)
#define OC0   0
#define OC1   BSZ
#define OC2   (2 * BSZ)
#define OQ    (3 * BSZ)
#define OLOSS (3 * BSZ + BSZ * DIM)

__device__ __forceinline__ unsigned fkey(float f) {
  unsigned b = __float_as_uint(f);
  return (b & 0x80000000u) ? ~b : (b | 0x80000000u);
}
__device__ __forceinline__ float fkeyinv(unsigned k) {
  return __uint_as_float((k & 0x80000000u) ? (k ^ 0x80000000u) : ~k);
}

// Load this lane's 4 codebook columns (cols 4*lane..4*lane+3) into registers,
// scaled by `scale`; also return per-column squared norms (of the raw values).
__device__ __forceinline__ void load_cbregs(const float* __restrict__ cb, int lane,
                                            float scale, float cbr[4][DIM], float c2[4]) {
#pragma unroll
  for (int c = 0; c < 4; ++c) {
    const float4* p = reinterpret_cast<const float4*>(cb + (4 * lane + c) * DIM);
    float s = 0.f;
#pragma unroll
    for (int k = 0; k < 8; ++k) {
      float4 v = p[k];
      cbr[c][4 * k + 0] = v.x * scale;
      cbr[c][4 * k + 1] = v.y * scale;
      cbr[c][4 * k + 2] = v.z * scale;
      cbr[c][4 * k + 3] = v.w * scale;
      s = fmaf(v.x, v.x, s); s = fmaf(v.y, v.y, s);
      s = fmaf(v.z, v.z, s); s = fmaf(v.w, v.w, s);
    }
    c2[c] = s;
  }
}

// v[c] += dot(cbr[c], row)  (row read via uniform LDS broadcast, float4 at a time)
__device__ __forceinline__ void dot4(const float* zr, const float cbr[4][DIM], float v[4]) {
#pragma unroll
  for (int d = 0; d < DIM; d += 4) {
    float4 rv = *reinterpret_cast<const float4*>(zr + d);
#pragma unroll
    for (int c = 0; c < 4; ++c) {
      v[c] = fmaf(cbr[c][d + 0], rv.x, v[c]);
      v[c] = fmaf(cbr[c][d + 1], rv.y, v[c]);
      v[c] = fmaf(cbr[c][d + 2], rv.z, v[c]);
      v[c] = fmaf(cbr[c][d + 3], rv.w, v[c]);
    }
  }
}

__global__ void init_k(unsigned* __restrict__ wsu) {
  if (threadIdx.x == 0) {
    wsu[WS_SSQ]  = 0u;            // 0.0f
    wsu[WS_MINK] = 0xFFFFFFFFu;
    wsu[WS_MAXK] = 0u;
  }
}

__device__ __forceinline__ void argmin_phase(const float* __restrict__ cb, const float* zl,
                                             const float* rsq, int* codel, int lane, int wid) {
  float cbr[4][DIM], c2[4];
  load_cbregs(cb, lane, 1.0f, cbr, c2);
  for (int rr = 0; rr < CHUNK / 4; ++rr) {
    int row = (CHUNK / 4) * wid + rr;
    float v[4] = {0.f, 0.f, 0.f, 0.f};
    dot4(&zl[row * LROW], cbr, v);
    float r2 = rsq[row];
    float bv = (r2 + c2[0]) - 2.0f * v[0];
    int bj = 4 * lane;
#pragma unroll
    for (int c = 1; c < 4; ++c) {
      float dd = (r2 + c2[c]) - 2.0f * v[c];
      if (dd < bv) { bv = dd; bj = 4 * lane + c; }
    }
#pragma unroll
    for (int m = 1; m < 64; m <<= 1) {
      float ov = __shfl_xor(bv, m);
      int oj = __shfl_xor(bj, m);
      if (ov < bv || (ov == bv && oj < bj)) { bv = ov; bj = oj; }
    }
    if (lane == 0) codel[row] = bj;
  }
}

// zl[row] -= cb[code[row]]; accumulate per-row squared norms into rsq (pre-zeroed).
__device__ __forceinline__ void remap_phase(const float* __restrict__ cb, float* zl,
                                            float* rsq, const int* codel, int tid) {
  int row = tid & (CHUNK - 1);
  int half = tid >> 7;
  const float* cbg = cb + codel[row] * DIM;
  float local = 0.f;
#pragma unroll
  for (int k = 0; k < 16; ++k) {
    int d = half * 16 + k;
    float v = zl[row * LROW + d] - cbg[d];
    zl[row * LROW + d] = v;
    local = fmaf(v, v, local);
  }
  atomicAdd(&rsq[row], local);
}

__global__ __launch_bounds__(256) void stageA_k(const float* __restrict__ z,
                                                const float* __restrict__ cb0,
                                                const float* __restrict__ cb1,
                                                const float* __restrict__ cb2,
                                                float* __restrict__ out,
                                                unsigned* __restrict__ wsu,
                                                float* __restrict__ wsf) {
  __shared__ float zl[CHUNK * LROW];
  __shared__ float rsq[CHUNK];
  __shared__ int codel[CHUNK];
  __shared__ float red[4];
  const int tid = threadIdx.x, lane = tid & 63, wid = tid >> 6;
  const long base = (long)blockIdx.x * CHUNK;

  // stage z chunk into LDS (coalesced float4)
#pragma unroll
  for (int g = 0; g < 4; ++g) {
    int f4 = g * 256 + tid;
    float4 v = reinterpret_cast<const float4*>(z + base * DIM)[f4];
    int row = f4 >> 3, d = (f4 & 7) * 4;
    *reinterpret_cast<float4*>(&zl[row * LROW + d]) = v;
  }
  __syncthreads();
  if (tid < CHUNK) {
    float s = 0.f;
#pragma unroll
    for (int d = 0; d < DIM; ++d) { float x = zl[tid * LROW + d]; s = fmaf(x, x, s); }
    rsq[tid] = s;
  }
  __syncthreads();

  float loss_acc = 0.f;

  // ---- level 0: argmin vs cb0, remap to r1
  argmin_phase(cb0, zl, rsq, codel, lane, wid);
  __syncthreads();
  if (tid < CHUNK) { out[OC0 + base + tid] = (float)codel[tid]; rsq[tid] = 0.f; }
  __syncthreads();
  remap_phase(cb0, zl, rsq, codel, tid);
  __syncthreads();
  if (tid < CHUNK) loss_acc += rsq[tid];   // sum ||r1||^2

  // ---- level 1: argmin vs cb1, remap to r2
  argmin_phase(cb1, zl, rsq, codel, lane, wid);
  __syncthreads();
  if (tid < CHUNK) { out[OC1 + base + tid] = (float)codel[tid]; rsq[tid] = 0.f; }
  __syncthreads();
  remap_phase(cb1, zl, rsq, codel, tid);
  __syncthreads();
  if (tid < CHUNK) loss_acc += rsq[tid];   // sum ||r2||^2

  // write residual2 (staged into d_out quantized region; overwritten by final_k)
#pragma unroll
  for (int g = 0; g < 16; ++g) {
    int flat = g * 256 + tid;
    out[OQ + base * DIM + flat] = zl[(flat >> 5) * LROW + (flat & 31)];
  }

  // ---- level 2: global min/max of full distances
  {
    float cbr[4][DIM], c2[4];
    load_cbregs(cb2, lane, 1.0f, cbr, c2);
    float dmn = 3.4e38f, dmx = -3.4e38f;
    for (int rr = 0; rr < CHUNK / 4; ++rr) {
      int row = (CHUNK / 4) * wid + rr;
      float v[4] = {0.f, 0.f, 0.f, 0.f};
      dot4(&zl[row * LROW], cbr, v);
      float r2 = rsq[row];
#pragma unroll
      for (int c = 0; c < 4; ++c) {
        float dd = (r2 + c2[c]) - 2.0f * v[c];
        dmn = fminf(dmn, dd);
        dmx = fmaxf(dmx, dd);
      }
    }
#pragma unroll
    for (int m = 1; m < 64; m <<= 1) {
      dmn = fminf(dmn, __shfl_xor(dmn, m));
      dmx = fmaxf(dmx, __shfl_xor(dmx, m));
    }
    if (lane == 0) {
      atomicMin(&wsu[WS_MINK], fkey(dmn));
      atomicMax(&wsu[WS_MAXK], fkey(dmx));
    }
  }

  // block loss reduce -> global
#pragma unroll
  for (int m = 1; m < 64; m <<= 1) loss_acc += __shfl_xor(loss_acc, m);
  if (lane == 0) red[wid] = loss_acc;
  __syncthreads();
  if (tid == 0) atomicAdd(&wsf[WS_SSQ], red[0] + red[1] + red[2] + red[3]);
}

__global__ void prep_k(const float* __restrict__ cb2, unsigned* __restrict__ wsu,
                       float* __restrict__ wsf) {
  int j = threadIdx.x;  // 256 threads
  float dmin = fkeyinv(wsu[WS_MINK]);
  float dmax = fkeyinv(wsu[WS_MAXK]);
  float mid = (dmax + dmin) * 0.5f;
  float amp = fmaxf(dmax - mid, 1e-5f);
  float t = 1.0f / (amp * SKEPS);
  if (j == 0) wsf[WS_TWOT] = 2.0f * t;
  float s = 0.f;
#pragma unroll
  for (int d = 0; d < DIM; ++d) { float c = cb2[j * DIM + d]; s = fmaf(c, c, s); }
  wsf[WS_W + j] = -t * s;   // w^0 = -t*c2 (beta=0 in potential form)
}

__global__ __launch_bounds__(256) void iter_k(const float* __restrict__ resid,
                                              const float* __restrict__ cb2,
                                              const float* __restrict__ wsf,
                                              float* __restrict__ partials) {
  __shared__ float zl[CHUNK * LROW];
  __shared__ float sigsh[4][KK];
  const int tid = threadIdx.x, lane = tid & 63, wid = tid >> 6;
  const long base = (long)blockIdx.x * CHUNK;
  const float twot = wsf[WS_TWOT];
  float cbr[4][DIM], c2d[4], wc[4];
  load_cbregs(cb2, lane, twot, cbr, c2d);
#pragma unroll
  for (int c = 0; c < 4; ++c) wc[c] = wsf[WS_W + 4 * lane + c];
#pragma unroll
  for (int g = 0; g < 4; ++g) {
    int f4 = g * 256 + tid;
    float4 v = reinterpret_cast<const float4*>(resid + base * DIM)[f4];
    int row = f4 >> 3, d = (f4 & 7) * 4;
    *reinterpret_cast<float4*>(&zl[row * LROW + d]) = v;
  }
  __syncthreads();
  float sg0 = 0.f, sg1 = 0.f, sg2 = 0.f, sg3 = 0.f;
  for (int rr = 0; rr < CHUNK / 4; ++rr) {
    int row = (CHUNK / 4) * wid + rr;
    float v[4] = {wc[0], wc[1], wc[2], wc[3]};   // v = M + w
    dot4(&zl[row * LROW], cbr, v);
    float m = fmaxf(fmaxf(v[0], v[1]), fmaxf(v[2], v[3]));
#pragma unroll
    for (int s = 1; s < 64; s <<= 1) m = fmaxf(m, __shfl_xor(m, s));
    float e0 = __expf(v[0] - m), e1 = __expf(v[1] - m);
    float e2 = __expf(v[2] - m), e3 = __expf(v[3] - m);
    float ss = (e0 + e1) + (e2 + e3);
#pragma unroll
    for (int s = 1; s < 64; s <<= 1) ss += __shfl_xor(ss, s);
    float rinv = 1.0f / ss;    // row-softmax normalizer; sigma += p_ij
    sg0 = fmaf(e0, rinv, sg0); sg1 = fmaf(e1, rinv, sg1);
    sg2 = fmaf(e2, rinv, sg2); sg3 = fmaf(e3, rinv, sg3);
  }
  sigsh[wid][4 * lane + 0] = sg0;
  sigsh[wid][4 * lane + 1] = sg1;
  sigsh[wid][4 * lane + 2] = sg2;
  sigsh[wid][4 * lane + 3] = sg3;
  __syncthreads();
  partials[(long)blockIdx.x * KK + tid] =
      sigsh[0][tid] + sigsh[1][tid] + sigsh[2][tid] + sigsh[3][tid];
}

__global__ __launch_bounds__(256) void reducew_k(const float* __restrict__ partials,
                                                 float* __restrict__ wsf) {
  const int j = blockIdx.x, tid = threadIdx.x, lane = tid & 63, wid = tid >> 6;
  __shared__ float red[4];
  float s = 0.f;
  for (int i = tid; i < NBLK; i += 256) s += partials[(long)i * KK + j];
#pragma unroll
  for (int m = 1; m < 64; m <<= 1) s += __shfl_xor(s, m);
  if (lane == 0) red[wid] = s;
  __syncthreads();
  if (tid == 0) {
    float sig = red[0] + red[1] + red[2] + red[3];
    // w += log(B/K) - log(sigma); clamp guards early-iteration underflow columns
    wsf[WS_W + j] += 6.9314718055994531f - logf(fmaxf(sig, 1e-30f));
  }
}

__global__ __launch_bounds__(256) void final_k(const float* __restrict__ z,
                                               const float* __restrict__ cb2,
                                               float* __restrict__ out,
                                               float* __restrict__ wsf) {
  __shared__ float zl[CHUNK * LROW];
  __shared__ int codel[CHUNK];
  __shared__ float red[4];
  const int tid = threadIdx.x, lane = tid & 63, wid = tid >> 6;
  const long base = (long)blockIdx.x * CHUNK;
  const float twot = wsf[WS_TWOT];
  float cbr[4][DIM], c2d[4], wc[4];
  load_cbregs(cb2, lane, twot, cbr, c2d);
#pragma unroll
  for (int c = 0; c < 4; ++c) wc[c] = wsf[WS_W + 4 * lane + c];
  const float* resid = out + OQ;
#pragma unroll
  for (int g = 0; g < 4; ++g) {
    int f4 = g * 256 + tid;
    float4 v = reinterpret_cast<const float4*>(resid + base * DIM)[f4];
    int row = f4 >> 3, d = (f4 & 7) * 4;
    *reinterpret_cast<float4*>(&zl[row * LROW + d]) = v;
  }
  __syncthreads();
  for (int rr = 0; rr < CHUNK / 4; ++rr) {
    int row = (CHUNK / 4) * wid + rr;
    float v[4] = {wc[0], wc[1], wc[2], wc[3]};
    dot4(&zl[row * LROW], cbr, v);
    float bv = v[0];
    int bj = 4 * lane;
#pragma unroll
    for (int c = 1; c < 4; ++c) {
      if (v[c] > bv) { bv = v[c]; bj = 4 * lane + c; }
    }
#pragma unroll
    for (int m = 1; m < 64; m <<= 1) {
      float ov = __shfl_xor(bv, m);
      int oj = __shfl_xor(bj, m);
      if (ov > bv || (ov == bv && oj < bj)) { bv = ov; bj = oj; }
    }
    if (lane == 0) codel[row] = bj;
  }
  __syncthreads();
  if (tid < CHUNK) out[OC2 + base + tid] = (float)codel[tid];
  float loss_acc = 0.f;
#pragma unroll
  for (int g = 0; g < 16; ++g) {
    int flat = g * 256 + tid;
    int row = flat >> 5, d = flat & 31;
    float e = cb2[codel[row] * DIM + d];
    float r = zl[row * LROW + d];                 // residual2
    float q = z[base * DIM + flat] - r + e;       // e0+e1+e2 = z - r2 + e2
    out[OQ + base * DIM + flat] = q;
    float r3 = r - e;
    loss_acc = fmaf(r3, r3, loss_acc);            // sum ||r3||^2
  }
#pragma unroll
  for (int m = 1; m < 64; m <<= 1) loss_acc += __shfl_xor(loss_acc, m);
  if (lane == 0) red[wid] = loss_acc;
  __syncthreads();
  if (tid == 0) atomicAdd(&wsf[WS_SSQ], red[0] + red[1] + red[2] + red[3]);
}

__global__ void losswrite_k(float* __restrict__ out, const float* __restrict__ wsf) {
  if (threadIdx.x == 0) out[OLOSS] = 1.25f * wsf[WS_SSQ] / 8388608.0f;
}

extern "C" void kernel_launch(void* const* d_in, const int* in_sizes, int n_in,
                              void* d_out, int out_size, void* d_ws, size_t ws_size,
                              hipStream_t stream) {
  const float* z   = (const float*)d_in[0];
  const float* cb0 = (const float*)d_in[1];
  const float* cb1 = (const float*)d_in[2];
  const float* cb2 = (const float*)d_in[3];
  float* out = (float*)d_out;
  float* wsf = (float*)d_ws;
  unsigned* wsu = (unsigned*)d_ws;
  float* partials = wsf + WS_PART;   // needs (512 + 2048*256)*4 ~= 2.1 MB of ws

  init_k<<<1, 64, 0, stream>>>(wsu);
  stageA_k<<<NBLK, 256, 0, stream>>>(z, cb0, cb1, cb2, out, wsu, wsf);
  prep_k<<<1, 256, 0, stream>>>(cb2, wsu, wsf);
  for (int it = 0; it < NIT; ++it) {
    iter_k<<<NBLK, 256, 0, stream>>>(out + OQ, cb2, wsf, partials);
    reducew_k<<<KK, 256, 0, stream>>>(partials, wsf);
  }
  final_k<<<NBLK, 256, 0, stream>>>(z, cb2, out, wsf);
  losswrite_k<<<1, 64, 0, stream>>>(out, wsf);
}

// Round 2
// 5087.081 us; speedup vs baseline: 1.1143x; 1.1143x over previous
//
#include <hip/hip_runtime.h>

// ResidualQuantizer: 3-level RVQ, levels 0/1 argmin, level 2 = 50-iter log-domain
// Sinkhorn in potential form, computed in the exp2 domain:
//   vt_ij = twot*cross(r_i,c_j) + w_j           (twot = 2*t*log2e)
//   rowLSE2_i = log2-LSE_j(vt_ij)
//   sigma_j = sum_i 2^(vt_ij - rowLSE2_i)       (terms <= 1)
//   w_j    += log2(B/K) - log2(sigma_j)
//   codes2_i = argmax_j vt_ij  (scale>0 -> same argmax as natural domain)
// sigma accumulated as fixed-point u64 atomics (order-independent => deterministic).
// w recursion is computed redundantly by every block; block 0 persists it.

#define BSZ   262144
#define DIM   32
#define KK    256
#define CHUNK 128
#define NBLK  (BSZ / CHUNK)   // 2048
#define LROW  36              // padded LDS row stride (144B, 16B-aligned)
#define SKEPS 0.003f
#define NIT   50

// workspace float offsets
#define WS_SSQ  0
#define WS_MINK 1
#define WS_MAXK 2
#define WS_TWOT 3
#define WS_W0   256   // 256 floats (initial w, log2-scaled)
#define WS_WA   512   // w slot A
#define WS_WB   768   // w slot B
#define WS_SIGB 4096  // byte offset of 3 x 256 u64 sigma slots

// d_out float offsets (return order: codes0, codes1, codes2, quantized, loss)
#define OC0   0
#define OC1   BSZ
#define OC2   (2 * BSZ)
#define OQ    (3 * BSZ)
#define OLOSS (3 * BSZ + BSZ * DIM)

#if __has_builtin(__builtin_amdgcn_exp2f)
#define EXP2(x) __builtin_amdgcn_exp2f(x)
#else
#define EXP2(x) exp2f(x)
#endif

#if __has_builtin(__builtin_amdgcn_update_dpp)
#define ROR16(x, N)                                                            \
  __int_as_float(__builtin_amdgcn_update_dpp(__float_as_int(x),                \
                 __float_as_int(x), 0x120 + (N), 0xF, 0xF, false))
#else
#define ROR16(x, N) __shfl_xor((x), (N))
#endif

__device__ __forceinline__ float wred_max(float x) {
  x = fmaxf(x, ROR16(x, 1));
  x = fmaxf(x, ROR16(x, 2));
  x = fmaxf(x, ROR16(x, 4));
  x = fmaxf(x, ROR16(x, 8));
  x = fmaxf(x, __shfl_xor(x, 16));
  x = fmaxf(x, __shfl_xor(x, 32));
  return x;
}
__device__ __forceinline__ float wred_min(float x) {
  x = fminf(x, ROR16(x, 1));
  x = fminf(x, ROR16(x, 2));
  x = fminf(x, ROR16(x, 4));
  x = fminf(x, ROR16(x, 8));
  x = fminf(x, __shfl_xor(x, 16));
  x = fminf(x, __shfl_xor(x, 32));
  return x;
}
__device__ __forceinline__ float wred_sum(float x) {
  x += ROR16(x, 1);
  x += ROR16(x, 2);
  x += ROR16(x, 4);
  x += ROR16(x, 8);
  x += __shfl_xor(x, 16);
  x += __shfl_xor(x, 32);
  return x;
}

__device__ __forceinline__ unsigned fkey(float f) {
  unsigned b = __float_as_uint(f);
  return (b & 0x80000000u) ? ~b : (b | 0x80000000u);
}
__device__ __forceinline__ float fkeyinv(unsigned k) {
  return __uint_as_float((k & 0x80000000u) ? (k ^ 0x80000000u) : ~k);
}

__device__ __forceinline__ void load_cbregs(const float* __restrict__ cb, int lane,
                                            float scale, float cbr[4][DIM], float c2[4]) {
#pragma unroll
  for (int c = 0; c < 4; ++c) {
    const float4* p = reinterpret_cast<const float4*>(cb + (4 * lane + c) * DIM);
    float s = 0.f;
#pragma unroll
    for (int k = 0; k < 8; ++k) {
      float4 v = p[k];
      cbr[c][4 * k + 0] = v.x * scale;
      cbr[c][4 * k + 1] = v.y * scale;
      cbr[c][4 * k + 2] = v.z * scale;
      cbr[c][4 * k + 3] = v.w * scale;
      s = fmaf(v.x, v.x, s); s = fmaf(v.y, v.y, s);
      s = fmaf(v.z, v.z, s); s = fmaf(v.w, v.w, s);
    }
    c2[c] = s;
  }
}

// 4 rows x 4 cols dot accumulate; zr = first row, consecutive rows stride LROW.
__device__ __forceinline__ void dot4x4(const float* zr, const float cbr[4][DIM],
                                       float v[4][4]) {
#pragma unroll
  for (int d = 0; d < DIM; d += 4) {
#pragma unroll
    for (int q = 0; q < 4; ++q) {
      float4 a = *reinterpret_cast<const float4*>(zr + q * LROW + d);
#pragma unroll
      for (int c = 0; c < 4; ++c) {
        v[q][c] = fmaf(cbr[c][d + 0], a.x, v[q][c]);
        v[q][c] = fmaf(cbr[c][d + 1], a.y, v[q][c]);
        v[q][c] = fmaf(cbr[c][d + 2], a.z, v[q][c]);
        v[q][c] = fmaf(cbr[c][d + 3], a.w, v[q][c]);
      }
    }
  }
}

__global__ void init_k(unsigned* __restrict__ wsu, unsigned long long* __restrict__ sig0) {
  sig0[threadIdx.x] = 0ull;
  if (threadIdx.x == 0) {
    wsu[WS_SSQ]  = 0u;
    wsu[WS_MINK] = 0xFFFFFFFFu;
    wsu[WS_MAXK] = 0u;
  }
}

__device__ __forceinline__ void argmin_phase(const float* __restrict__ cb, const float* zl,
                                             const float* rsq, int* codel, int lane, int wid) {
  float cbr[4][DIM], c2[4];
  load_cbregs(cb, lane, 1.0f, cbr, c2);
  for (int rb = 0; rb < 8; ++rb) {
    const int r0 = wid * 32 + rb * 4;
    float v[4][4];
#pragma unroll
    for (int q = 0; q < 4; ++q) { v[q][0] = 0.f; v[q][1] = 0.f; v[q][2] = 0.f; v[q][3] = 0.f; }
    dot4x4(&zl[r0 * LROW], cbr, v);
    float d0[4], d1[4], d2[4], d3[4], bq[4], mq[4];
#pragma unroll
    for (int q = 0; q < 4; ++q) {
      float r2 = rsq[r0 + q];
      d0[q] = fmaf(-2.f, v[q][0], r2 + c2[0]);
      d1[q] = fmaf(-2.f, v[q][1], r2 + c2[1]);
      d2[q] = fmaf(-2.f, v[q][2], r2 + c2[2]);
      d3[q] = fmaf(-2.f, v[q][3], r2 + c2[3]);
      bq[q] = fminf(fminf(d0[q], d1[q]), fminf(d2[q], d3[q]));
    }
#pragma unroll
    for (int q = 0; q < 4; ++q) mq[q] = wred_min(bq[q]);
#pragma unroll
    for (int q = 0; q < 4; ++q) {
      int cbi = (d0[q] == mq[q]) ? 0 : ((d1[q] == mq[q]) ? 1 : ((d2[q] == mq[q]) ? 2 : 3));
      unsigned long long bl = __ballot(bq[q] == mq[q]);
      int src = __ffsll(bl) - 1;
      int code = __shfl(4 * lane + cbi, src);
      if (lane == 0) codel[r0 + q] = code;
    }
  }
}

__device__ __forceinline__ void remap_phase(const float* __restrict__ cb, float* zl,
                                            float* rsq, const int* codel, int tid) {
  int row = tid & (CHUNK - 1);
  int half = tid >> 7;
  const float* cbg = cb + codel[row] * DIM;
  float local = 0.f;
#pragma unroll
  for (int k = 0; k < 16; ++k) {
    int d = half * 16 + k;
    float v = zl[row * LROW + d] - cbg[d];
    zl[row * LROW + d] = v;
    local = fmaf(v, v, local);
  }
  atomicAdd(&rsq[row], local);
}

__global__ __launch_bounds__(256, 2) void stageA_k(const float* __restrict__ z,
                                                   const float* __restrict__ cb0,
                                                   const float* __restrict__ cb1,
                                                   const float* __restrict__ cb2,
                                                   float* __restrict__ out,
                                                   unsigned* __restrict__ wsu,
                                                   float* __restrict__ wsf) {
  __shared__ float zl[CHUNK * LROW];
  __shared__ float rsq[CHUNK];
  __shared__ int codel[CHUNK];
  __shared__ float red[4];
  const int tid = threadIdx.x, lane = tid & 63, wid = tid >> 6;
  const long base = (long)blockIdx.x * CHUNK;

#pragma unroll
  for (int g = 0; g < 4; ++g) {
    int f4 = g * 256 + tid;
    float4 v = reinterpret_cast<const float4*>(z + base * DIM)[f4];
    int row = f4 >> 3, d = (f4 & 7) * 4;
    *reinterpret_cast<float4*>(&zl[row * LROW + d]) = v;
  }
  __syncthreads();
  if (tid < CHUNK) {
    float s = 0.f;
#pragma unroll
    for (int d = 0; d < DIM; ++d) { float x = zl[tid * LROW + d]; s = fmaf(x, x, s); }
    rsq[tid] = s;
  }
  __syncthreads();

  float loss_acc = 0.f;

  // ---- level 0
  argmin_phase(cb0, zl, rsq, codel, lane, wid);
  __syncthreads();
  if (tid < CHUNK) { out[OC0 + base + tid] = (float)codel[tid]; rsq[tid] = 0.f; }
  __syncthreads();
  remap_phase(cb0, zl, rsq, codel, tid);
  __syncthreads();
  if (tid < CHUNK) loss_acc += rsq[tid];

  // ---- level 1
  argmin_phase(cb1, zl, rsq, codel, lane, wid);
  __syncthreads();
  if (tid < CHUNK) { out[OC1 + base + tid] = (float)codel[tid]; rsq[tid] = 0.f; }
  __syncthreads();
  remap_phase(cb1, zl, rsq, codel, tid);
  __syncthreads();
  if (tid < CHUNK) loss_acc += rsq[tid];

  // residual2 -> staged in quantized region of d_out
#pragma unroll
  for (int g = 0; g < 16; ++g) {
    int flat = g * 256 + tid;
    out[OQ + base * DIM + flat] = zl[(flat >> 5) * LROW + (flat & 31)];
  }

  // ---- level 2 global min/max of distances
  {
    float cbr[4][DIM], c2[4];
    load_cbregs(cb2, lane, 1.0f, cbr, c2);
    float dmn = 3.4e38f, dmx = -3.4e38f;
    for (int rb = 0; rb < 8; ++rb) {
      const int r0 = wid * 32 + rb * 4;
      float v[4][4];
#pragma unroll
      for (int q = 0; q < 4; ++q) { v[q][0] = 0.f; v[q][1] = 0.f; v[q][2] = 0.f; v[q][3] = 0.f; }
      dot4x4(&zl[r0 * LROW], cbr, v);
#pragma unroll
      for (int q = 0; q < 4; ++q) {
        float r2 = rsq[r0 + q];
#pragma unroll
        for (int c = 0; c < 4; ++c) {
          float dd = fmaf(-2.f, v[q][c], r2 + c2[c]);
          dmn = fminf(dmn, dd);
          dmx = fmaxf(dmx, dd);
        }
      }
    }
    dmn = wred_min(dmn);
    dmx = wred_max(dmx);
    if (lane == 0) {
      atomicMin(&wsu[WS_MINK], fkey(dmn));
      atomicMax(&wsu[WS_MAXK], fkey(dmx));
    }
  }

  loss_acc = wred_sum(loss_acc);
  if (lane == 0) red[wid] = loss_acc;
  __syncthreads();
  if (tid == 0) atomicAdd(&wsf[WS_SSQ], red[0] + red[1] + red[2] + red[3]);
}

__global__ void prep_k(const float* __restrict__ cb2, unsigned* __restrict__ wsu,
                       float* __restrict__ wsf) {
  int j = threadIdx.x;  // 256 threads
  float dmin = fkeyinv(wsu[WS_MINK]);
  float dmax = fkeyinv(wsu[WS_MAXK]);
  float mid = (dmax + dmin) * 0.5f;
  float amp = fmaxf(dmax - mid, 1e-5f);
  float t = 1.0f / (amp * SKEPS);
  const float L2E = 1.4426950408889634f;
  if (j == 0) wsf[WS_TWOT] = 2.0f * t * L2E;
  float s = 0.f;
#pragma unroll
  for (int d = 0; d < DIM; ++d) { float c = cb2[j * DIM + d]; s = fmaf(c, c, s); }
  wsf[WS_W0 + j] = -t * L2E * s;
}

__global__ __launch_bounds__(256, 2) void iter_k(const float* __restrict__ resid,
                                                 const float* __restrict__ cb2,
                                                 const float* __restrict__ wsf,
                                                 const float* __restrict__ w_rd,
                                                 float* __restrict__ w_wr,
                                                 const unsigned long long* __restrict__ s_rd,
                                                 unsigned long long* __restrict__ s_wr,
                                                 unsigned long long* __restrict__ s_zr,
                                                 int first) {
  __shared__ float zl[CHUNK * LROW];
  __shared__ float wsh[KK];
  __shared__ float sigsh[4][KK];
  const int tid = threadIdx.x, lane = tid & 63, wid = tid >> 6;
  const long base = (long)blockIdx.x * CHUNK;

  {
    // w_k = w_{k-1} + log2(B/K) + 24 - log2(sigma_raw); 24 undoes the 2^24 fixed-point.
    float wj = first ? w_rd[tid]
                     : w_rd[tid] + 34.0f - log2f(fmaxf((float)s_rd[tid], 1.0f));
    wsh[tid] = wj;
    if (blockIdx.x == 0) { w_wr[tid] = wj; s_zr[tid] = 0ull; }
  }
#pragma unroll
  for (int g = 0; g < 4; ++g) {
    int f4 = g * 256 + tid;
    float4 vv = reinterpret_cast<const float4*>(resid + base * DIM)[f4];
    int row = f4 >> 3, d = (f4 & 7) * 4;
    *reinterpret_cast<float4*>(&zl[row * LROW + d]) = vv;
  }
  const float twot = wsf[WS_TWOT];
  float cbr[4][DIM], c2d[4];
  load_cbregs(cb2, lane, twot, cbr, c2d);
  __syncthreads();
  float wc[4];
#pragma unroll
  for (int c = 0; c < 4; ++c) wc[c] = wsh[4 * lane + c];

  float sg[4] = {0.f, 0.f, 0.f, 0.f};
  for (int rb = 0; rb < 8; ++rb) {
    const int r0 = wid * 32 + rb * 4;
    float v[4][4];
#pragma unroll
    for (int q = 0; q < 4; ++q) { v[q][0] = wc[0]; v[q][1] = wc[1]; v[q][2] = wc[2]; v[q][3] = wc[3]; }
    dot4x4(&zl[r0 * LROW], cbr, v);
    float m[4], ss[4];
#pragma unroll
    for (int q = 0; q < 4; ++q)
      m[q] = fmaxf(fmaxf(v[q][0], v[q][1]), fmaxf(v[q][2], v[q][3]));
#pragma unroll
    for (int q = 0; q < 4; ++q) m[q] = wred_max(m[q]);
#pragma unroll
    for (int q = 0; q < 4; ++q) {
      v[q][0] = EXP2(v[q][0] - m[q]); v[q][1] = EXP2(v[q][1] - m[q]);
      v[q][2] = EXP2(v[q][2] - m[q]); v[q][3] = EXP2(v[q][3] - m[q]);
      ss[q] = (v[q][0] + v[q][1]) + (v[q][2] + v[q][3]);
    }
#pragma unroll
    for (int q = 0; q < 4; ++q) ss[q] = wred_sum(ss[q]);
#pragma unroll
    for (int q = 0; q < 4; ++q) {
      float ri = __builtin_amdgcn_rcpf(ss[q]);
      sg[0] = fmaf(v[q][0], ri, sg[0]);
      sg[1] = fmaf(v[q][1], ri, sg[1]);
      sg[2] = fmaf(v[q][2], ri, sg[2]);
      sg[3] = fmaf(v[q][3], ri, sg[3]);
    }
  }
#pragma unroll
  for (int c = 0; c < 4; ++c) sigsh[wid][4 * lane + c] = sg[c];
  __syncthreads();
  float s = sigsh[0][tid] + sigsh[1][tid] + sigsh[2][tid] + sigsh[3][tid];
  // fixed-point u64 accumulation: order-independent => deterministic
  atomicAdd(&s_wr[tid], (unsigned long long)fmaf(s, 16777216.0f, 0.5f));
}

__global__ __launch_bounds__(256, 2) void final_k(const float* __restrict__ z,
                                                  const float* __restrict__ cb2,
                                                  float* __restrict__ out,
                                                  const float* __restrict__ wsf,
                                                  float* __restrict__ wssq,
                                                  const float* __restrict__ w_rd,
                                                  const unsigned long long* __restrict__ s_rd) {
  __shared__ float zl[CHUNK * LROW];
  __shared__ float wsh[KK];
  __shared__ int codel[CHUNK];
  __shared__ float red[4];
  const int tid = threadIdx.x, lane = tid & 63, wid = tid >> 6;
  const long base = (long)blockIdx.x * CHUNK;

  wsh[tid] = w_rd[tid] + 34.0f - log2f(fmaxf((float)s_rd[tid], 1.0f));

  const float* resid = out + OQ;
#pragma unroll
  for (int g = 0; g < 4; ++g) {
    int f4 = g * 256 + tid;
    float4 vv = reinterpret_cast<const float4*>(resid + base * DIM)[f4];
    int row = f4 >> 3, d = (f4 & 7) * 4;
    *reinterpret_cast<float4*>(&zl[row * LROW + d]) = vv;
  }
  const float twot = wsf[WS_TWOT];
  float cbr[4][DIM], c2d[4];
  load_cbregs(cb2, lane, twot, cbr, c2d);
  __syncthreads();
  float wc[4];
#pragma unroll
  for (int c = 0; c < 4; ++c) wc[c] = wsh[4 * lane + c];

  for (int rb = 0; rb < 8; ++rb) {
    const int r0 = wid * 32 + rb * 4;
    float v[4][4];
#pragma unroll
    for (int q = 0; q < 4; ++q) { v[q][0] = wc[0]; v[q][1] = wc[1]; v[q][2] = wc[2]; v[q][3] = wc[3]; }
    dot4x4(&zl[r0 * LROW], cbr, v);
    float bq[4], mq[4];
#pragma unroll
    for (int q = 0; q < 4; ++q)
      bq[q] = fmaxf(fmaxf(v[q][0], v[q][1]), fmaxf(v[q][2], v[q][3]));
#pragma unroll
    for (int q = 0; q < 4; ++q) mq[q] = wred_max(bq[q]);
#pragma unroll
    for (int q = 0; q < 4; ++q) {
      int cbi = (v[q][0] == mq[q]) ? 0 : ((v[q][1] == mq[q]) ? 1 : ((v[q][2] == mq[q]) ? 2 : 3));
      unsigned long long bl = __ballot(bq[q] == mq[q]);
      int src = __ffsll(bl) - 1;
      int code = __shfl(4 * lane + cbi, src);
      if (lane == 0) codel[r0 + q] = code;
    }
  }
  __syncthreads();
  if (tid < CHUNK) out[OC2 + base + tid] = (float)codel[tid];
  float loss_acc = 0.f;
#pragma unroll
  for (int g = 0; g < 16; ++g) {
    int flat = g * 256 + tid;
    int row = flat >> 5, d = flat & 31;
    float e = cb2[codel[row] * DIM + d];
    float r = zl[row * LROW + d];
    float q = z[base * DIM + flat] - r + e;
    out[OQ + base * DIM + flat] = q;
    float r3 = r - e;
    loss_acc = fmaf(r3, r3, loss_acc);
  }
  loss_acc = wred_sum(loss_acc);
  if (lane == 0) red[wid] = loss_acc;
  __syncthreads();
  if (tid == 0) atomicAdd(&wssq[WS_SSQ], red[0] + red[1] + red[2] + red[3]);
}

__global__ void losswrite_k(float* __restrict__ out, const float* __restrict__ wsf) {
  if (threadIdx.x == 0) out[OLOSS] = 1.25f * wsf[WS_SSQ] / 8388608.0f;
}

extern "C" void kernel_launch(void* const* d_in, const int* in_sizes, int n_in,
                              void* d_out, int out_size, void* d_ws, size_t ws_size,
                              hipStream_t stream) {
  const float* z   = (const float*)d_in[0];
  const float* cb0 = (const float*)d_in[1];
  const float* cb1 = (const float*)d_in[2];
  const float* cb2 = (const float*)d_in[3];
  float* out = (float*)d_out;
  float* wsf = (float*)d_ws;
  unsigned* wsu = (unsigned*)d_ws;
  unsigned long long* sig = (unsigned long long*)((char*)d_ws + WS_SIGB);

  init_k<<<1, 256, 0, stream>>>(wsu, sig);  // zeroes sigma slot 0
  stageA_k<<<NBLK, 256, 0, stream>>>(z, cb0, cb1, cb2, out, wsu, wsf);
  prep_k<<<1, 256, 0, stream>>>(cb2, wsu, wsf);
  for (int it = 0; it < NIT; ++it) {
    const float* w_rd = (it == 0) ? (wsf + WS_W0) : (wsf + WS_WA + ((it - 1) & 1) * KK);
    float* w_wr = wsf + WS_WA + (it & 1) * KK;
    const unsigned long long* s_rd = sig + KK * ((it + 2) % 3);
    unsigned long long* s_wr = sig + KK * (it % 3);
    unsigned long long* s_zr = sig + KK * ((it + 1) % 3);
    iter_k<<<NBLK, 256, 0, stream>>>(out + OQ, cb2, wsf, w_rd, w_wr, s_rd, s_wr, s_zr,
                                     it == 0 ? 1 : 0);
  }
  final_k<<<NBLK, 256, 0, stream>>>(z, cb2, out, wsf, wsf,
                                    wsf + WS_WA + ((NIT - 1) & 1) * KK,
                                    sig + KK * ((NIT - 1) % 3));
  losswrite_k<<<1, 64, 0, stream>>>(out, wsf);
}